// Round 1
// baseline (1408.471 us; speedup 1.0000x reference)
//
#include <hip/hip_runtime.h>
#include <math.h>

#define N_NODES 100000
#define N_EDGES 1600000
#define IN_CH 256
#define HID_CH 128
#define OUT_CH 64

// ---------------- small elementwise kernels ----------------

__global__ void k_fill(float* __restrict__ p, float v, int n) {
    int i = blockIdx.x * blockDim.x + threadIdx.x;
    if (i < n) p[i] = v;
}

__global__ void k_count(const int* __restrict__ dst, float* __restrict__ deg) {
    int e = blockIdx.x * blockDim.x + threadIdx.x;
    if (e < N_EDGES) atomicAdd(&deg[dst[e]], 1.0f);
}

__global__ void k_rsqrt_inplace(float* __restrict__ deg) {
    int i = blockIdx.x * blockDim.x + threadIdx.x;
    if (i < N_NODES) deg[i] = rsqrtf(deg[i]);  // deg >= 1 always (self loop)
}

// agg[i,c] = dinv[i]^2 * h[i,c]   (self-loop contribution, also zero-inits agg)
template <int C>
__global__ void k_init_agg(const float* __restrict__ h, const float* __restrict__ dinv,
                           float* __restrict__ agg) {
    int t = blockIdx.x * blockDim.x + threadIdx.x;
    if (t >= N_NODES * C) return;
    int i = t / C;
    float w = dinv[i];
    agg[t] = w * w * h[t];
}

// agg[dst,c] += dinv[src]*dinv[dst] * h[src,c]
template <int C>
__global__ __launch_bounds__(256) void k_scatter(const int* __restrict__ src,
                                                 const int* __restrict__ dst,
                                                 const float* __restrict__ dinv,
                                                 const float* __restrict__ h,
                                                 float* __restrict__ agg) {
    constexpr int EPB = 256 / C;  // edges per block
    int le = threadIdx.x / C;
    int c  = threadIdx.x % C;
    int e  = blockIdx.x * EPB + le;
    if (e >= N_EDGES) return;
    int s = src[e], d = dst[e];
    float w = dinv[s] * dinv[d];
    atomicAdd(&agg[(size_t)d * C + c], w * h[(size_t)s * C + c]);
}

// out[i,c] = agg[i,c] + b[c]  (optional relu). out may alias agg.
template <int C, bool RELU>
__global__ void k_bias(const float* __restrict__ agg, const float* __restrict__ b,
                       float* __restrict__ out) {
    int t = blockIdx.x * blockDim.x + threadIdx.x;
    if (t >= N_NODES * C) return;
    int c = t % C;
    float v = agg[t] + b[c];
    if (RELU) v = fmaxf(v, 0.0f);
    out[t] = v;
}

// ---------------- fp32 tiled GEMM: C[M,NOUT] = A[M,K] @ W[K,NOUT] ----------------
// BM=64, BN=64, BK=16; 256 threads, each computes 4x4.
template <int K, int NOUT>
__global__ __launch_bounds__(256) void k_gemm(const float* __restrict__ A,
                                              const float* __restrict__ W,
                                              float* __restrict__ C) {
    constexpr int BM = 64, BN = 64, BK = 16;
    __shared__ float As[BK][BM];  // transposed A tile: As[k][m]
    __shared__ float Bs[BK][BN];

    int tid = threadIdx.x;
    int tx = tid % 16;  // output column group
    int ty = tid / 16;  // output row group
    int m0 = blockIdx.x * BM;
    int n0 = blockIdx.y * BN;

    float acc[4][4] = {};

    for (int k0 = 0; k0 < K; k0 += BK) {
        // load A tile (64 rows x 16 cols), one float4 per thread
        {
            int row = tid / 4;     // 0..63
            int c4  = tid % 4;     // 0..3 -> cols c4*4..c4*4+3
            int gr = m0 + row;
            float4 v = make_float4(0.f, 0.f, 0.f, 0.f);
            if (gr < N_NODES)
                v = *reinterpret_cast<const float4*>(&A[(size_t)gr * K + k0 + c4 * 4]);
            As[c4 * 4 + 0][row] = v.x;
            As[c4 * 4 + 1][row] = v.y;
            As[c4 * 4 + 2][row] = v.z;
            As[c4 * 4 + 3][row] = v.w;
        }
        // load W tile (16 rows x 64 cols), one float4 per thread
        {
            int row = tid / 16;    // 0..15
            int c4  = tid % 16;    // 0..15
            float4 v = *reinterpret_cast<const float4*>(&W[(size_t)(k0 + row) * NOUT + n0 + c4 * 4]);
            *reinterpret_cast<float4*>(&Bs[row][c4 * 4]) = v;
        }
        __syncthreads();

        #pragma unroll
        for (int kk = 0; kk < BK; ++kk) {
            float4 av = *reinterpret_cast<const float4*>(&As[kk][ty * 4]);
            float4 bv = *reinterpret_cast<const float4*>(&Bs[kk][tx * 4]);
            float a[4] = {av.x, av.y, av.z, av.w};
            float b[4] = {bv.x, bv.y, bv.z, bv.w};
            #pragma unroll
            for (int i = 0; i < 4; ++i)
                #pragma unroll
                for (int j = 0; j < 4; ++j)
                    acc[i][j] += a[i] * b[j];
        }
        __syncthreads();
    }

    #pragma unroll
    for (int i = 0; i < 4; ++i) {
        int gr = m0 + ty * 4 + i;
        if (gr < N_NODES) {
            float4 v = make_float4(acc[i][0], acc[i][1], acc[i][2], acc[i][3]);
            *reinterpret_cast<float4*>(&C[(size_t)gr * NOUT + n0 + tx * 4]) = v;
        }
    }
}

// ---------------- decoder: out[e] = sigmoid(dot(z[src[e]], z[dst[e]])) ----------------
// 16 lanes per edge, float4 loads, shfl_xor reduce within 16-lane group.
__global__ __launch_bounds__(256) void k_decode(const int* __restrict__ esrc,
                                                const int* __restrict__ edst,
                                                const float* __restrict__ z,
                                                float* __restrict__ out) {
    int tid = threadIdx.x;
    int e = blockIdx.x * 16 + tid / 16;
    int q = tid % 16;
    if (e >= N_EDGES) return;
    int s = esrc[e], d = edst[e];
    float4 a = reinterpret_cast<const float4*>(&z[(size_t)s * OUT_CH])[q];
    float4 b = reinterpret_cast<const float4*>(&z[(size_t)d * OUT_CH])[q];
    float dot = a.x * b.x + a.y * b.y + a.z * b.z + a.w * b.w;
    dot += __shfl_xor(dot, 1);
    dot += __shfl_xor(dot, 2);
    dot += __shfl_xor(dot, 4);
    dot += __shfl_xor(dot, 8);
    if (q == 0) out[e] = 1.0f / (1.0f + expf(-dot));
}

// ---------------- launch ----------------

extern "C" void kernel_launch(void* const* d_in, const int* in_sizes, int n_in,
                              void* d_out, int out_size, void* d_ws, size_t ws_size,
                              hipStream_t stream) {
    const float* x  = (const float*)d_in[0];
    const int*   ei = (const int*)d_in[1];
    const float* W1 = (const float*)d_in[2];
    const float* b1 = (const float*)d_in[3];
    const float* W2 = (const float*)d_in[4];
    const float* b2 = (const float*)d_in[5];
    float* out = (float*)d_out;

    const int* src = ei;             // edge_index row 0
    const int* dst = ei + N_EDGES;   // edge_index row 1

    // workspace layout
    char* ws = (char*)d_ws;
    float* dinv = (float*)ws;                                  // N floats (400 KB)
    float* bufA = (float*)(ws + (1 << 20));                    // N*128 floats (51.2 MB)
    float* bufB = bufA + (size_t)N_NODES * HID_CH;             // N*128 floats (51.2 MB)
    // layer 1: h1 -> bufA, agg1 -> bufB (then bias+relu in place in bufB)
    // layer 2: h2 -> bufA[0 : N*64], agg2 -> bufA[N*64 : N*128] (then bias in place = z)
    float* h1   = bufA;
    float* agg1 = bufB;
    float* h1r  = bufB;  // in place
    float* h2   = bufA;
    float* agg2 = bufA + (size_t)N_NODES * OUT_CH;
    float* z    = agg2;  // in place

    // --- gcn_norm: deg (init 1.0 for self loop) -> dinv ---
    k_fill<<<(N_NODES + 255) / 256, 256, 0, stream>>>(dinv, 1.0f, N_NODES);
    k_count<<<(N_EDGES + 255) / 256, 256, 0, stream>>>(dst, dinv);
    k_rsqrt_inplace<<<(N_NODES + 255) / 256, 256, 0, stream>>>(dinv);

    // --- layer 1 ---
    {
        dim3 grid((N_NODES + 63) / 64, HID_CH / 64);
        k_gemm<IN_CH, HID_CH><<<grid, 256, 0, stream>>>(x, W1, h1);
    }
    k_init_agg<HID_CH><<<(N_NODES * HID_CH + 255) / 256, 256, 0, stream>>>(h1, dinv, agg1);
    k_scatter<HID_CH><<<N_EDGES / (256 / HID_CH), 256, 0, stream>>>(src, dst, dinv, h1, agg1);
    k_bias<HID_CH, true><<<(N_NODES * HID_CH + 255) / 256, 256, 0, stream>>>(agg1, b1, h1r);

    // --- layer 2 ---
    {
        dim3 grid((N_NODES + 63) / 64, OUT_CH / 64);
        k_gemm<HID_CH, OUT_CH><<<grid, 256, 0, stream>>>(h1r, W2, h2);
    }
    k_init_agg<OUT_CH><<<(N_NODES * OUT_CH + 255) / 256, 256, 0, stream>>>(h2, dinv, agg2);
    k_scatter<OUT_CH><<<N_EDGES / (256 / OUT_CH), 256, 0, stream>>>(src, dst, dinv, h2, agg2);
    k_bias<OUT_CH, false><<<(N_NODES * OUT_CH + 255) / 256, 256, 0, stream>>>(agg2, b2, z);

    // --- decoder ---
    k_decode<<<N_EDGES / 16, 256, 0, stream>>>(src, dst, z, out);
}

// Round 2
// 616.681 us; speedup vs baseline: 2.2840x; 2.2840x over previous
//
#include <hip/hip_runtime.h>
#include <math.h>

#define N_NODES 100000
#define N_EDGES 1600000
#define IN_CH 256
#define HID_CH 128
#define OUT_CH 64
#define NBLK_SCAN ((N_NODES + 255) / 256)   // 391

// ---------------- degree / norm ----------------

__global__ void k_zero_int(int* __restrict__ p, int n) {
    int i = blockIdx.x * blockDim.x + threadIdx.x;
    if (i < n) p[i] = 0;
}

__global__ void k_count_int(const int* __restrict__ dst, int* __restrict__ deg) {
    int e = blockIdx.x * blockDim.x + threadIdx.x;
    if (e < N_EDGES) atomicAdd(&deg[dst[e]], 1);
}

// dinv[i] = rsqrt(deg[i] + 1 [self loop]); also cursor[i] = rowoff[i]
__global__ void k_dinv_cursor(const int* __restrict__ deg, const int* __restrict__ rowoff,
                              float* __restrict__ dinv, int* __restrict__ cursor) {
    int i = blockIdx.x * blockDim.x + threadIdx.x;
    if (i >= N_NODES) return;
    dinv[i] = rsqrtf((float)deg[i] + 1.0f);
    cursor[i] = rowoff[i];
}

// ---------------- exclusive prefix scan over deg -> rowoff ----------------

__global__ void k_scan_block(const int* __restrict__ deg, int* __restrict__ excl,
                             int* __restrict__ bsums) {
    __shared__ int tmp[256];
    int i = blockIdx.x * 256 + threadIdx.x;
    int v = (i < N_NODES) ? deg[i] : 0;
    tmp[threadIdx.x] = v;
    __syncthreads();
    for (int off = 1; off < 256; off <<= 1) {
        int t = (threadIdx.x >= off) ? tmp[threadIdx.x - off] : 0;
        __syncthreads();
        tmp[threadIdx.x] += t;
        __syncthreads();
    }
    if (i < N_NODES) excl[i] = tmp[threadIdx.x] - v;
    if (threadIdx.x == 255) bsums[blockIdx.x] = tmp[255];
}

__global__ void k_scan_bsums(int* __restrict__ bsums) {  // single block of 512
    __shared__ int tmp[512];
    int v = (threadIdx.x < NBLK_SCAN) ? bsums[threadIdx.x] : 0;
    tmp[threadIdx.x] = v;
    __syncthreads();
    for (int off = 1; off < 512; off <<= 1) {
        int t = (threadIdx.x >= off) ? tmp[threadIdx.x - off] : 0;
        __syncthreads();
        tmp[threadIdx.x] += t;
        __syncthreads();
    }
    if (threadIdx.x < NBLK_SCAN) bsums[threadIdx.x] = tmp[threadIdx.x] - v;
}

__global__ void k_scan_add(int* __restrict__ excl, const int* __restrict__ bsums) {
    int i = blockIdx.x * 256 + threadIdx.x;
    if (i < N_NODES) excl[i] += bsums[blockIdx.x];
}

// ---------------- CSR fill: csr_src[pos] = src[e] grouped by dst ----------------

__global__ void k_fill_csr(const int* __restrict__ src, const int* __restrict__ dst,
                           int* __restrict__ cursor, int* __restrict__ csr_src) {
    int e = blockIdx.x * blockDim.x + threadIdx.x;
    if (e >= N_EDGES) return;
    int d = dst[e];
    int pos = atomicAdd(&cursor[d], 1);
    csr_src[pos] = src[e];
}

// ---------------- fp32 tiled GEMM with dinv-scaled epilogue ----------------
// C[m,n] = dinv[m] * sum_k A[m,k] W[k,n]
template <int K, int NOUT>
__global__ __launch_bounds__(256) void k_gemm(const float* __restrict__ A,
                                              const float* __restrict__ W,
                                              const float* __restrict__ dinv,
                                              float* __restrict__ C) {
    constexpr int BM = 64, BN = 64, BK = 16;
    __shared__ float As[BK][BM];
    __shared__ float Bs[BK][BN];

    int tid = threadIdx.x;
    int tx = tid % 16;
    int ty = tid / 16;
    int m0 = blockIdx.x * BM;
    int n0 = blockIdx.y * BN;

    float acc[4][4] = {};

    for (int k0 = 0; k0 < K; k0 += BK) {
        {
            int row = tid / 4;
            int c4  = tid % 4;
            int gr = m0 + row;
            float4 v = make_float4(0.f, 0.f, 0.f, 0.f);
            if (gr < N_NODES)
                v = *reinterpret_cast<const float4*>(&A[(size_t)gr * K + k0 + c4 * 4]);
            As[c4 * 4 + 0][row] = v.x;
            As[c4 * 4 + 1][row] = v.y;
            As[c4 * 4 + 2][row] = v.z;
            As[c4 * 4 + 3][row] = v.w;
        }
        {
            int row = tid / 16;
            int c4  = tid % 16;
            float4 v = *reinterpret_cast<const float4*>(&W[(size_t)(k0 + row) * NOUT + n0 + c4 * 4]);
            *reinterpret_cast<float4*>(&Bs[row][c4 * 4]) = v;
        }
        __syncthreads();

        #pragma unroll
        for (int kk = 0; kk < BK; ++kk) {
            float4 av = *reinterpret_cast<const float4*>(&As[kk][ty * 4]);
            float4 bv = *reinterpret_cast<const float4*>(&Bs[kk][tx * 4]);
            float a[4] = {av.x, av.y, av.z, av.w};
            float b[4] = {bv.x, bv.y, bv.z, bv.w};
            #pragma unroll
            for (int i = 0; i < 4; ++i)
                #pragma unroll
                for (int j = 0; j < 4; ++j)
                    acc[i][j] += a[i] * b[j];
        }
        __syncthreads();
    }

    #pragma unroll
    for (int i = 0; i < 4; ++i) {
        int gr = m0 + ty * 4 + i;
        if (gr < N_NODES) {
            float w = dinv[gr];
            float4 v = make_float4(w * acc[i][0], w * acc[i][1], w * acc[i][2], w * acc[i][3]);
            *reinterpret_cast<float4*>(&C[(size_t)gr * NOUT + n0 + tx * 4]) = v;
        }
    }
}

// ---------------- gather aggregation ----------------
// out[d,:] = [relu]( dinv[d] * (hs[d,:] + sum_{e in csr row d} hs[src_e,:]) + b )
// hs is pre-scaled by dinv (GEMM epilogue). TPN = C/4 threads per node, float4 each.
template <int C, bool RELU>
__global__ __launch_bounds__(256) void k_gather_agg(const int* __restrict__ rowoff,
                                                    const int* __restrict__ csr_src,
                                                    const float* __restrict__ hs,
                                                    const float* __restrict__ dinv,
                                                    const float* __restrict__ b,
                                                    float* __restrict__ outp) {
    constexpr int TPN = C / 4;
    constexpr int NPB = 256 / TPN;
    int t = threadIdx.x;
    int node = blockIdx.x * NPB + t / TPN;
    int q = t % TPN;
    if (node >= N_NODES) return;

    int beg = rowoff[node];
    int end = (node + 1 < N_NODES) ? rowoff[node + 1] : N_EDGES;

    float4 acc = reinterpret_cast<const float4*>(&hs[(size_t)node * C])[q];  // self loop

    int j = beg;
    for (; j + 1 < end; j += 2) {
        int s0 = csr_src[j];
        int s1 = csr_src[j + 1];
        float4 v0 = reinterpret_cast<const float4*>(&hs[(size_t)s0 * C])[q];
        float4 v1 = reinterpret_cast<const float4*>(&hs[(size_t)s1 * C])[q];
        acc.x += v0.x + v1.x;
        acc.y += v0.y + v1.y;
        acc.z += v0.z + v1.z;
        acc.w += v0.w + v1.w;
    }
    if (j < end) {
        int s0 = csr_src[j];
        float4 v0 = reinterpret_cast<const float4*>(&hs[(size_t)s0 * C])[q];
        acc.x += v0.x;
        acc.y += v0.y;
        acc.z += v0.z;
        acc.w += v0.w;
    }

    float w = dinv[node];
    float4 bb = reinterpret_cast<const float4*>(b)[q];
    float4 o = make_float4(w * acc.x + bb.x, w * acc.y + bb.y,
                           w * acc.z + bb.z, w * acc.w + bb.w);
    if (RELU) {
        o.x = fmaxf(o.x, 0.0f);
        o.y = fmaxf(o.y, 0.0f);
        o.z = fmaxf(o.z, 0.0f);
        o.w = fmaxf(o.w, 0.0f);
    }
    reinterpret_cast<float4*>(&outp[(size_t)node * C])[q] = o;
}

// ---------------- decoder ----------------

__global__ __launch_bounds__(256) void k_decode(const int* __restrict__ esrc,
                                                const int* __restrict__ edst,
                                                const float* __restrict__ z,
                                                float* __restrict__ out) {
    int tid = threadIdx.x;
    int e = blockIdx.x * 16 + tid / 16;
    int q = tid % 16;
    if (e >= N_EDGES) return;
    int s = esrc[e], d = edst[e];
    float4 a = reinterpret_cast<const float4*>(&z[(size_t)s * OUT_CH])[q];
    float4 b = reinterpret_cast<const float4*>(&z[(size_t)d * OUT_CH])[q];
    float dot = a.x * b.x + a.y * b.y + a.z * b.z + a.w * b.w;
    dot += __shfl_xor(dot, 1);
    dot += __shfl_xor(dot, 2);
    dot += __shfl_xor(dot, 4);
    dot += __shfl_xor(dot, 8);
    if (q == 0) out[e] = 1.0f / (1.0f + expf(-dot));
}

// ---------------- launch ----------------

extern "C" void kernel_launch(void* const* d_in, const int* in_sizes, int n_in,
                              void* d_out, int out_size, void* d_ws, size_t ws_size,
                              hipStream_t stream) {
    const float* x  = (const float*)d_in[0];
    const int*   ei = (const int*)d_in[1];
    const float* W1 = (const float*)d_in[2];
    const float* b1 = (const float*)d_in[3];
    const float* W2 = (const float*)d_in[4];
    const float* b2 = (const float*)d_in[5];
    float* out = (float*)d_out;

    const int* src = ei;
    const int* dst = ei + N_EDGES;

    // workspace layout
    char* ws = (char*)d_ws;
    int*   deg     = (int*)ws;                               // 400 KB
    int*   rowoff  = deg + N_NODES;                          // 400 KB
    int*   cursor  = rowoff + N_NODES;                       // 400 KB
    int*   bsums   = cursor + N_NODES;                       // 2 KB
    float* dinv    = (float*)(ws + (2 << 20));               // 400 KB
    int*   csr_src = (int*)(ws + (3 << 20));                 // 6.4 MB
    float* bufA    = (float*)(ws + (10 << 20));              // 51.2 MB
    float* bufB    = bufA + (size_t)N_NODES * HID_CH;        // 51.2 MB

    float* hs1 = bufA;                               // dinv-scaled x@W1
    float* h1r = bufB;                               // relu(agg1 + b1)
    float* hs2 = bufA;                               // dinv-scaled h1r@W2
    float* z   = bufA + (size_t)N_NODES * OUT_CH;    // agg2 + b2

    // --- norm + CSR build ---
    k_zero_int<<<(N_NODES + 255) / 256, 256, 0, stream>>>(deg, N_NODES);
    k_count_int<<<(N_EDGES + 255) / 256, 256, 0, stream>>>(dst, deg);
    k_scan_block<<<NBLK_SCAN, 256, 0, stream>>>(deg, rowoff, bsums);
    k_scan_bsums<<<1, 512, 0, stream>>>(bsums);
    k_scan_add<<<NBLK_SCAN, 256, 0, stream>>>(rowoff, bsums);
    k_dinv_cursor<<<(N_NODES + 255) / 256, 256, 0, stream>>>(deg, rowoff, dinv, cursor);
    k_fill_csr<<<(N_EDGES + 255) / 256, 256, 0, stream>>>(src, dst, cursor, csr_src);

    // --- layer 1 ---
    {
        dim3 grid((N_NODES + 63) / 64, HID_CH / 64);
        k_gemm<IN_CH, HID_CH><<<grid, 256, 0, stream>>>(x, W1, dinv, hs1);
    }
    k_gather_agg<HID_CH, true><<<(N_NODES + 7) / 8, 256, 0, stream>>>(
        rowoff, csr_src, hs1, dinv, b1, h1r);

    // --- layer 2 ---
    {
        dim3 grid((N_NODES + 63) / 64, OUT_CH / 64);
        k_gemm<HID_CH, OUT_CH><<<grid, 256, 0, stream>>>(h1r, W2, dinv, hs2);
    }
    k_gather_agg<OUT_CH, false><<<(N_NODES + 15) / 16, 256, 0, stream>>>(
        rowoff, csr_src, hs2, dinv, b2, z);

    // --- decoder ---
    k_decode<<<N_EDGES / 16, 256, 0, stream>>>(src, dst, z, out);
}